// Round 2
// baseline (2881.976 us; speedup 1.0000x reference)
//
#include <hip/hip_runtime.h>

#define D 256
#define KCODES 8192
#define NROWS 32768

// main kernel tiling
#define BN 64
#define BK 256
#define DCH 32
#define KSPLIT 2

// d_out layout (floats): quantized[8388608] | indices[32768] | commit | codebook | total
#define OUT_Q 0
#define OUT_IDX 8388608
#define OUT_LOSS (8388608 + 32768)

// ws layout (floats): xsq[32768] | esq[8192] | loss[1] | pad | keys[32768] u64
#define WS_XSQ 0
#define WS_ESQ 32768
#define WS_LOSS (32768 + 8192)
#define WS_KEYS_F (32768 + 8192 + 8)   // byte off 163904, 8-aligned

// Replicates numpy pairwise_sum semantics for n=256 contiguous f32 (see R1).
__global__ __launch_bounds__(256) void rowsq_kernel(
    const float* __restrict__ src, float* __restrict__ dst, int nrows,
    float* loss_zero, unsigned long long* keys_init) {
  if (loss_zero && blockIdx.x == 0 && threadIdx.x == 0) *loss_zero = 0.0f;
  int r = blockIdx.x * 256 + threadIdx.x;
  if (r >= nrows) return;
  if (keys_init) keys_init[r] = 0xFFFFFFFFFFFFFFFFull;
  const float4* p4 = (const float4*)(src + (size_t)r * D);
  float total = 0.0f;
  #pragma unroll
  for (int half = 0; half < 2; ++half) {
    float r8[8];
    float4 v0 = p4[half * 32 + 0];
    float4 v1 = p4[half * 32 + 1];
    r8[0] = __fmul_rn(v0.x, v0.x); r8[1] = __fmul_rn(v0.y, v0.y);
    r8[2] = __fmul_rn(v0.z, v0.z); r8[3] = __fmul_rn(v0.w, v0.w);
    r8[4] = __fmul_rn(v1.x, v1.x); r8[5] = __fmul_rn(v1.y, v1.y);
    r8[6] = __fmul_rn(v1.z, v1.z); r8[7] = __fmul_rn(v1.w, v1.w);
    #pragma unroll
    for (int i8 = 1; i8 < 16; ++i8) {
      v0 = p4[half * 32 + i8 * 2];
      v1 = p4[half * 32 + i8 * 2 + 1];
      r8[0] = __fadd_rn(r8[0], __fmul_rn(v0.x, v0.x));
      r8[1] = __fadd_rn(r8[1], __fmul_rn(v0.y, v0.y));
      r8[2] = __fadd_rn(r8[2], __fmul_rn(v0.z, v0.z));
      r8[3] = __fadd_rn(r8[3], __fmul_rn(v0.w, v0.w));
      r8[4] = __fadd_rn(r8[4], __fmul_rn(v1.x, v1.x));
      r8[5] = __fadd_rn(r8[5], __fmul_rn(v1.y, v1.y));
      r8[6] = __fadd_rn(r8[6], __fmul_rn(v1.z, v1.z));
      r8[7] = __fadd_rn(r8[7], __fmul_rn(v1.w, v1.w));
    }
    float s = __fadd_rn(__fadd_rn(__fadd_rn(r8[0], r8[1]), __fadd_rn(r8[2], r8[3])),
                        __fadd_rn(__fadd_rn(r8[4], r8[5]), __fadd_rn(r8[6], r8[7])));
    total = (half == 0) ? s : __fadd_rn(total, s);
  }
  dst[r] = total;
}

// Tiled dot + argmin over a K-half. Block: 256 threads, 64 rows x 4096 codes.
// Partial argmin merged across the 2 K-halves via device-scope atomicMin on
// packed u64 (score_bits<<32)|idx; score>0 so f32 bits are order-monotone,
// and smaller idx wins ties (matches np first-index argmin).
__global__ __launch_bounds__(256, 4) void vq_argmin_kernel(
    const float* __restrict__ x, const float* __restrict__ emb,
    const float* __restrict__ xsq, const float* __restrict__ esq,
    unsigned long long* __restrict__ keys) {
  __shared__ float Alds[DCH][BN];   // 8 KB
  __shared__ float Blds[DCH][BK];   // 32 KB
  const int tid = threadIdx.x;
  const int tc = tid & 31;
  const int tr = tid >> 5;
  const int rowBase = blockIdx.x * BN;
  const int ktBase = blockIdx.y * (KCODES / KSPLIT);

  const int row_a = tid & 63;        // A: row within tile
  const int dj = (tid >> 6) * 8;     // A: 8-float d-offset within chunk

  float xs[8];
  #pragma unroll
  for (int i = 0; i < 8; ++i) xs[i] = xsq[rowBase + tr * 8 + i];

  unsigned long long best[8];
  #pragma unroll
  for (int i = 0; i < 8; ++i) best[i] = 0xFFFFFFFFFFFFFFFFull;

  for (int kt = ktBase; kt < ktBase + KCODES / KSPLIT; kt += BK) {
    float acc[8][8];
    #pragma unroll
    for (int i = 0; i < 8; ++i)
      #pragma unroll
      for (int j = 0; j < 8; ++j) acc[i][j] = 0.0f;

    // prologue: load chunk 0 into regs
    float4 aq0, aq1, bq[8];
    {
      const float4* ap = (const float4*)(x + (size_t)(rowBase + row_a) * D + dj);
      aq0 = ap[0]; aq1 = ap[1];
      const float4* bp = (const float4*)(emb + (size_t)(kt + tid) * D);
      #pragma unroll
      for (int jj = 0; jj < 8; ++jj) bq[jj] = bp[jj];
    }

    for (int dc = 0; dc < D / DCH; ++dc) {
      __syncthreads();   // previous chunk's compute done; LDS free
      Alds[dj + 0][row_a] = aq0.x; Alds[dj + 1][row_a] = aq0.y;
      Alds[dj + 2][row_a] = aq0.z; Alds[dj + 3][row_a] = aq0.w;
      Alds[dj + 4][row_a] = aq1.x; Alds[dj + 5][row_a] = aq1.y;
      Alds[dj + 6][row_a] = aq1.z; Alds[dj + 7][row_a] = aq1.w;
      #pragma unroll
      for (int jj = 0; jj < 8; ++jj) {
        Blds[jj * 4 + 0][tid] = bq[jj].x;
        Blds[jj * 4 + 1][tid] = bq[jj].y;
        Blds[jj * 4 + 2][tid] = bq[jj].z;
        Blds[jj * 4 + 3][tid] = bq[jj].w;
      }
      __syncthreads();   // LDS ready
      // prefetch next chunk into regs (overlaps with compute below)
      if (dc < D / DCH - 1) {
        const float4* ap = (const float4*)(x + (size_t)(rowBase + row_a) * D + (dc + 1) * DCH + dj);
        aq0 = ap[0]; aq1 = ap[1];
        const float4* bp = (const float4*)(emb + (size_t)(kt + tid) * D + (dc + 1) * DCH);
        #pragma unroll
        for (int jj = 0; jj < 8; ++jj) bq[jj] = bp[jj];
      }
      // 8x8 outer-product accumulate over this d-chunk
      #pragma unroll 8
      for (int d = 0; d < DCH; ++d) {
        const float4 av0 = *(const float4*)(&Alds[d][tr * 8]);
        const float4 av1 = *(const float4*)(&Alds[d][tr * 8 + 4]);
        const float4 bv0 = *(const float4*)(&Blds[d][tc * 8]);
        const float4 bv1 = *(const float4*)(&Blds[d][tc * 8 + 4]);
        const float av[8] = {av0.x, av0.y, av0.z, av0.w, av1.x, av1.y, av1.z, av1.w};
        const float bv[8] = {bv0.x, bv0.y, bv0.z, bv0.w, bv1.x, bv1.y, bv1.z, bv1.w};
        #pragma unroll
        for (int i = 0; i < 8; ++i)
          #pragma unroll
          for (int j = 0; j < 8; ++j)
            acc[i][j] = __builtin_fmaf(av[i], bv[j], acc[i][j]);
      }
    }

    // scoring epilogue for this K-tile (np f32 rounding replicated)
    const float4 e0 = *(const float4*)(esq + kt + tc * 8);
    const float4 e1 = *(const float4*)(esq + kt + tc * 8 + 4);
    const float es[8] = {e0.x, e0.y, e0.z, e0.w, e1.x, e1.y, e1.z, e1.w};
    #pragma unroll
    for (int i = 0; i < 8; ++i) {
      #pragma unroll
      for (int j = 0; j < 8; ++j) {
        float m2 = __fmul_rn(2.0f, acc[i][j]);
        float s1 = __fsub_rn(xs[i], m2);
        float s2 = __fadd_rn(s1, es[j]);
        unsigned long long kk =
            ((unsigned long long)__float_as_uint(s2) << 32) |
            (unsigned)(kt + tc * 8 + j);
        if (kk < best[i]) best[i] = kk;
      }
    }
  }

  // reduce argmin across the 32 col-group lanes, then merge K-halves
  #pragma unroll
  for (int i = 0; i < 8; ++i) {
    unsigned long long b = best[i];
    #pragma unroll
    for (int m = 16; m >= 1; m >>= 1) {
      unsigned long long o = __shfl_xor(b, m, 64);
      if (o < b) b = o;
    }
    if (tc == 0) {
      int row = rowBase + tr * 8 + i;
      atomicMin(&keys[row], b);
    }
  }
}

// Gather quantized rows + write index output + accumulate sum((x-q)^2).
__global__ __launch_bounds__(256) void gather_kernel(
    const float* __restrict__ x, const float* __restrict__ emb,
    const unsigned long long* __restrict__ keys, float* __restrict__ outq,
    float* __restrict__ out_idx, float* __restrict__ loss) {
  const int t = threadIdx.x;
  const int row = blockIdx.x * 64 + (t >> 2);
  const int d0 = (t & 3) * 64;
  const int idx = (int)(unsigned)(keys[row] & 0xFFFFFFFFull);
  if (d0 == 0) out_idx[row] = (float)idx;
  const float4* q4 = (const float4*)(emb + (size_t)idx * D + d0);
  const float4* x4 = (const float4*)(x + (size_t)row * D + d0);
  float4* o4 = (float4*)(outq + (size_t)row * D + d0);
  float s = 0.0f;
  #pragma unroll
  for (int j = 0; j < 16; ++j) {
    float4 q = q4[j];
    float4 xv = x4[j];
    o4[j] = q;
    float e0 = xv.x - q.x; s = __builtin_fmaf(e0, e0, s);
    float e1 = xv.y - q.y; s = __builtin_fmaf(e1, e1, s);
    float e2 = xv.z - q.z; s = __builtin_fmaf(e2, e2, s);
    float e3 = xv.w - q.w; s = __builtin_fmaf(e3, e3, s);
  }
  #pragma unroll
  for (int m = 32; m >= 1; m >>= 1) s += __shfl_xor(s, m, 64);
  __shared__ float wsum[4];
  if ((t & 63) == 0) wsum[t >> 6] = s;
  __syncthreads();
  if (t == 0) atomicAdd(loss, ((wsum[0] + wsum[1]) + (wsum[2] + wsum[3])));
}

__global__ void finalize_kernel(const float* __restrict__ loss,
                                float* __restrict__ out3) {
  if (threadIdx.x == 0 && blockIdx.x == 0) {
    float mean = *loss / 8388608.0f;   // exact: /2^23
    float commit = __fmul_rn(0.25f, mean);
    out3[0] = commit;
    out3[1] = mean;
    out3[2] = __fadd_rn(commit, mean);
  }
}

extern "C" void kernel_launch(void* const* d_in, const int* in_sizes, int n_in,
                              void* d_out, int out_size, void* d_ws, size_t ws_size,
                              hipStream_t stream) {
  const float* x = (const float*)d_in[0];    // [32768, 256]
  const float* emb = (const float*)d_in[1];  // [8192, 256]
  float* out = (float*)d_out;
  float* ws = (float*)d_ws;

  float* xsq = ws + WS_XSQ;
  float* esq = ws + WS_ESQ;
  float* lossacc = ws + WS_LOSS;
  unsigned long long* keys = (unsigned long long*)(ws + WS_KEYS_F);

  rowsq_kernel<<<NROWS / 256, 256, 0, stream>>>(x, xsq, NROWS, nullptr, keys);
  rowsq_kernel<<<KCODES / 256, 256, 0, stream>>>(emb, esq, KCODES, lossacc, nullptr);
  dim3 grid(NROWS / BN, KSPLIT);
  vq_argmin_kernel<<<grid, 256, 0, stream>>>(x, emb, xsq, esq, keys);
  gather_kernel<<<NROWS / 64, 256, 0, stream>>>(x, emb, keys, out + OUT_Q,
                                                out + OUT_IDX, lossacc);
  finalize_kernel<<<1, 64, 0, stream>>>(lossacc, out + OUT_LOSS);
}

// Round 4
// 1034.400 us; speedup vs baseline: 2.7861x; 2.7861x over previous
//
#include <hip/hip_runtime.h>

#define D 256
#define KCODES 8192
#define NROWS 32768

#define BN 64              // rows per block (4 waves x 16 rows)
#define CHUNK 64           // codes staged per LDS chunk
#define NCHUNK (KCODES / CHUNK)
#define CAP 128            // candidate cap per row
#define MD 4.5e-5f         // dot-space capture margin (see analysis)

typedef short short8 __attribute__((ext_vector_type(8)));
typedef float f32x4 __attribute__((ext_vector_type(4)));

// d_out layout (floats): quantized[8388608] | indices[32768] | commit | codebook | total
#define OUT_IDX 8388608
#define OUT_LOSS (8388608 + 32768)
// d_out scratch aliasing (bytes): xb16 @ 0 (16.78 MB), eb16 @ 16777216 (4.19 MB)
// written by prep, read by vq_filter, overwritten by gather afterwards.

// ws layout (floats): xsq[32768] | esq[8192] | loss[1]
#define WS_XSQ 0
#define WS_ESQ 32768
#define WS_LOSS (32768 + 8192)

// np-pairwise row sum-of-squares (bitwise, as in R1 -- proven) + bf16(RNE) copy.
__global__ __launch_bounds__(256) void prep_kernel(
    const float* __restrict__ src, float* __restrict__ sq,
    ushort* __restrict__ b16, int nrows, float* loss_zero) {
  if (loss_zero && blockIdx.x == 0 && threadIdx.x == 0) *loss_zero = 0.0f;
  int r = blockIdx.x * 256 + threadIdx.x;
  if (r >= nrows) return;
  const float4* p4 = (const float4*)(src + (size_t)r * D);
  uint4* o16 = (uint4*)(b16 + (size_t)r * D);
  float total = 0.0f;
  #pragma unroll
  for (int half = 0; half < 2; ++half) {
    float r8[8];
    #pragma unroll
    for (int i8 = 0; i8 < 16; ++i8) {
      float4 v0 = p4[half * 32 + i8 * 2];
      float4 v1 = p4[half * 32 + i8 * 2 + 1];
      float f[8] = {v0.x, v0.y, v0.z, v0.w, v1.x, v1.y, v1.z, v1.w};
      uint hh[8];
      #pragma unroll
      for (int j = 0; j < 8; ++j) {
        uint u = __float_as_uint(f[j]);
        hh[j] = (u + 0x7FFFu + ((u >> 16) & 1u)) >> 16;   // RNE f32->bf16
      }
      uint4 st;
      st.x = hh[0] | (hh[1] << 16); st.y = hh[2] | (hh[3] << 16);
      st.z = hh[4] | (hh[5] << 16); st.w = hh[6] | (hh[7] << 16);
      o16[half * 16 + i8] = st;
      #pragma unroll
      for (int j = 0; j < 8; ++j) {
        float p = __fmul_rn(f[j], f[j]);
        r8[j] = (i8 == 0) ? p : __fadd_rn(r8[j], p);
      }
    }
    float s = __fadd_rn(__fadd_rn(__fadd_rn(r8[0], r8[1]), __fadd_rn(r8[2], r8[3])),
                        __fadd_rn(__fadd_rn(r8[4], r8[5]), __fadd_rn(r8[6], r8[7])));
    total = (half == 0) ? s : __fadd_rn(total, s);
  }
  sq[r] = total;
}

// Coarse bf16-MFMA filter + exact rescore.
// Per block: 64 rows x all 8192 codes, chunked 64 codes/LDS tile.
// Phase 1: max-dot tracking + margin candidate collection (bf16 coarse).
// Phase 2: candidates rescored with R1's bit-exact f32 sequential-FMA dot and
//          np-rounded score; u64 key min == R1's winner => same pass behavior.
// MFMA note: A and B fragments are loaded with the SAME k-assignment
// (k = ks*32 + (lane>>4)*8 + j); any consistent bijection contracts correctly
// because the 16x16 family's A/B lane->k maps are symmetric.
__global__ __launch_bounds__(256, 2) void vq_filter_kernel(
    const ushort* __restrict__ xb, const ushort* __restrict__ eb,
    const float* __restrict__ x, const float* __restrict__ emb,
    const float* __restrict__ xsq, const float* __restrict__ esq,
    float* __restrict__ out_idx) {
  __shared__ __align__(16) char ldsb[32768 + BN * CAP * 2 + BN * 4];
  ushort* cand = (ushort*)(ldsb + 32768);
  unsigned* cnt = (unsigned*)(ldsb + 32768 + BN * CAP * 2);

  const int tid = threadIdx.x;
  const int w = tid >> 6;
  const int l = tid & 63;
  const int lg = l >> 4;     // k-subgroup; also row-subgroup of C
  const int lc = l & 15;     // A-row / B-col within tile; C-col
  const int rowBase = blockIdx.x * BN;

  if (tid < BN) cnt[tid] = 0;

  // A fragments (rows rowBase + w*16 + lc), k = ks*32 + lg*8 + {0..7}
  const int arow = rowBase + w * 16 + lc;
  short8 afr[8];
  #pragma unroll
  for (int ks = 0; ks < 8; ++ks)
    afr[ks] = *(const short8*)(xb + (size_t)arow * D + ks * 32 + lg * 8);

  // staging role: thread stages code n_w of the chunk, 16B slots sb..sb+7
  const int n_w = tid >> 2;
  const int sb = (tid & 3) * 8;
  uint4 bq[8];
  {
    const char* gp = (const char*)eb + (size_t)n_w * 512;
    #pragma unroll
    for (int i = 0; i < 8; ++i) bq[i] = *(const uint4*)(gp + (sb + i) * 16);
  }

  float maxd[4] = {-1e30f, -1e30f, -1e30f, -1e30f};
  float thr[4];

  for (int c = 0; c < NCHUNK; ++c) {
    __syncthreads();   // previous chunk's LDS reads done
    {
      char* wp = ldsb + (size_t)n_w * 512;
      #pragma unroll
      for (int i = 0; i < 8; ++i)
        *(uint4*)(wp + (((sb + i) ^ (n_w & 7)) * 16)) = bq[i];   // slot-XOR swizzle
    }
    __syncthreads();   // tile ready
    if (c < NCHUNK - 1) {
      const char* gp = (const char*)eb +
          (size_t)(c + 1) * CHUNK * 512 + (size_t)n_w * 512;
      #pragma unroll
      for (int i = 0; i < 8; ++i) bq[i] = *(const uint4*)(gp + (sb + i) * 16);
    }

    f32x4 acc[4];
    #pragma unroll
    for (int ct = 0; ct < 4; ++ct) acc[ct] = (f32x4){0.f, 0.f, 0.f, 0.f};
    #pragma unroll
    for (int ct = 0; ct < 4; ++ct) {
      const int n = lc + ct * 16;
      const char* rp = ldsb + (size_t)n * 512;
      #pragma unroll
      for (int ks = 0; ks < 8; ++ks) {
        const int sr = ks * 4 + lg;
        short8 bfr = *(const short8*)(rp + ((sr ^ (n & 7)) * 16));  // same swizzle
        acc[ct] = __builtin_amdgcn_mfma_f32_16x16x32_bf16(afr[ks], bfr, acc[ct], 0, 0, 0);
      }
    }

    // epilogue: shared running max per row, then margin appends
    #pragma unroll
    for (int reg = 0; reg < 4; ++reg) {
      float m = maxd[reg];
      #pragma unroll
      for (int ct = 0; ct < 4; ++ct) m = fmaxf(m, acc[ct][reg]);
      #pragma unroll
      for (int sh = 1; sh < 16; sh <<= 1) m = fmaxf(m, __shfl_xor(m, sh, 64));
      maxd[reg] = m;
      thr[reg] = m - MD;
    }
    #pragma unroll
    for (int ct = 0; ct < 4; ++ct) {
      #pragma unroll
      for (int reg = 0; reg < 4; ++reg) {
        if (acc[ct][reg] > thr[reg]) {
          int lrow = w * 16 + lg * 4 + reg;                 // C row map (verified)
          unsigned slot = atomicAdd(&cnt[lrow], 1u);
          if (slot < CAP)
            cand[lrow * CAP + slot] = (ushort)(c * CHUNK + ct * 16 + lc);
        }
      }
    }
  }
  __syncthreads();

  // Phase 2: exact rescore. One lane per candidate; dot is the strict
  // sequential d=0..255 fmaf chain on f32 inputs (bit-identical to R1).
  for (int r16 = 0; r16 < 16; ++r16) {
    const int lrow = w * 16 + r16;
    const int grow = rowBase + lrow;
    const float xs = xsq[grow];
    const int ncand = min((int)cnt[lrow], CAP);
    unsigned long long bestk = 0xFFFFFFFFFFFFFFFFull;
    const float4* x4 = (const float4*)(x + (size_t)grow * D);
    for (int ci = l; ci < ncand; ci += 64) {
      const int idx = cand[lrow * CAP + ci];
      const float4* e4 = (const float4*)(emb + (size_t)idx * D);
      float dot = 0.0f;
      #pragma unroll 8
      for (int q = 0; q < 64; ++q) {
        float4 xv = x4[q], ev = e4[q];
        dot = __builtin_fmaf(xv.x, ev.x, dot);
        dot = __builtin_fmaf(xv.y, ev.y, dot);
        dot = __builtin_fmaf(xv.z, ev.z, dot);
        dot = __builtin_fmaf(xv.w, ev.w, dot);
      }
      float s2 = __fadd_rn(__fsub_rn(xs, __fmul_rn(2.0f, dot)), esq[idx]);
      unsigned long long kk =
          ((unsigned long long)__float_as_uint(s2) << 32) | (unsigned)idx;
      if (kk < bestk) bestk = kk;
    }
    #pragma unroll
    for (int sh = 1; sh < 64; sh <<= 1) {
      unsigned long long o = __shfl_xor(bestk, sh, 64);
      if (o < bestk) bestk = o;
    }
    if (l == 0) out_idx[grow] = (float)(unsigned)(bestk & 0xFFFFFFFFull);
  }
}

// Gather quantized rows + accumulate sum((x-q)^2) into loss accumulator.
__global__ __launch_bounds__(256) void gather_kernel(
    const float* __restrict__ x, const float* __restrict__ emb,
    const float* __restrict__ idxf, float* __restrict__ outq,
    float* __restrict__ loss) {
  const int t = threadIdx.x;
  const int row = blockIdx.x * 64 + (t >> 2);
  const int d0 = (t & 3) * 64;
  const int idx = (int)idxf[row];
  const float4* q4 = (const float4*)(emb + (size_t)idx * D + d0);
  const float4* x4 = (const float4*)(x + (size_t)row * D + d0);
  float4* o4 = (float4*)(outq + (size_t)row * D + d0);
  float s = 0.0f;
  #pragma unroll
  for (int j = 0; j < 16; ++j) {
    float4 q = q4[j];
    float4 xv = x4[j];
    o4[j] = q;
    float e0 = xv.x - q.x; s = __builtin_fmaf(e0, e0, s);
    float e1 = xv.y - q.y; s = __builtin_fmaf(e1, e1, s);
    float e2 = xv.z - q.z; s = __builtin_fmaf(e2, e2, s);
    float e3 = xv.w - q.w; s = __builtin_fmaf(e3, e3, s);
  }
  #pragma unroll
  for (int m = 32; m >= 1; m >>= 1) s += __shfl_xor(s, m, 64);
  __shared__ float wsum[4];
  if ((t & 63) == 0) wsum[t >> 6] = s;
  __syncthreads();
  if (t == 0) atomicAdd(loss, ((wsum[0] + wsum[1]) + (wsum[2] + wsum[3])));
}

__global__ void finalize_kernel(const float* __restrict__ loss,
                                float* __restrict__ out3) {
  if (threadIdx.x == 0 && blockIdx.x == 0) {
    float mean = *loss / 8388608.0f;   // exact: /2^23
    float commit = __fmul_rn(0.25f, mean);
    out3[0] = commit;
    out3[1] = mean;
    out3[2] = __fadd_rn(commit, mean);
  }
}

extern "C" void kernel_launch(void* const* d_in, const int* in_sizes, int n_in,
                              void* d_out, int out_size, void* d_ws, size_t ws_size,
                              hipStream_t stream) {
  const float* x = (const float*)d_in[0];    // [32768, 256] f32
  const float* emb = (const float*)d_in[1];  // [8192, 256] f32
  float* out = (float*)d_out;
  float* ws = (float*)d_ws;

  float* xsq = ws + WS_XSQ;
  float* esq = ws + WS_ESQ;
  float* lossacc = ws + WS_LOSS;

  // scratch bf16 copies inside d_out's quantized region (overwritten by gather)
  ushort* xb = (ushort*)out;               // 16.78 MB
  ushort* eb = (ushort*)(out + 4194304);   //  4.19 MB, ends well before OUT_IDX

  prep_kernel<<<NROWS / 256, 256, 0, stream>>>(x, xsq, xb, NROWS, nullptr);
  prep_kernel<<<KCODES / 256, 256, 0, stream>>>(emb, esq, eb, KCODES, lossacc);
  vq_filter_kernel<<<NROWS / BN, 256, 0, stream>>>(xb, eb, x, emb, xsq, esq,
                                                   out + OUT_IDX);
  gather_kernel<<<NROWS / 64, 256, 0, stream>>>(x, emb, out + OUT_IDX, out, lossacc);
  finalize_kernel<<<1, 64, 0, stream>>>(lossacc, out + OUT_LOSS);
}

// Round 9
// 611.056 us; speedup vs baseline: 4.7164x; 1.6928x over previous
//
#include <hip/hip_runtime.h>

#define D 256
#define KCODES 8192
#define NROWS 32768

#define BN 64              // rows per block (4 waves x 16 rows)
#define CHUNK 64           // codes staged per LDS chunk
#define KSPLIT 2
#define CSPLIT (KCODES / KSPLIT / CHUNK)   // 64 chunks per block
#define CAP 48             // candidate cap per row (expected ~6)
#define MD 4.5e-5f         // dot-space capture margin (R3 analysis, R4-validated)

typedef short short8 __attribute__((ext_vector_type(8)));
typedef float f32x4 __attribute__((ext_vector_type(4)));

// d_out layout (floats): quantized[8388608] | indices[32768] | commit | codebook | total
#define OUT_IDX 8388608
#define OUT_LOSS (8388608 + 32768)
// d_out scratch aliasing: xb16 @ 0, eb16 @ float-off 4194304 (overwritten by gather)

// ws layout (floats): xsq[32768] | esq[8192] | loss[1] | pad | keys[32768] u64
#define WS_XSQ 0
#define WS_ESQ 32768
#define WS_LOSS (32768 + 8192)
#define WS_KEYS_F (32768 + 8192 + 8)

__device__ __forceinline__ void gload_lds16(const void* g, void* l) {
  __builtin_amdgcn_global_load_lds(
      (const __attribute__((address_space(1))) unsigned int*)g,
      (__attribute__((address_space(3))) unsigned int*)l, 16, 0, 0);
}

// np-pairwise row sum-of-squares (bitwise, R1-proven) + bf16(RNE) copy + inits.
__global__ __launch_bounds__(256) void prep_kernel(
    const float* __restrict__ src, float* __restrict__ sq,
    ushort* __restrict__ b16, int nrows, float* loss_zero,
    unsigned long long* keys_init) {
  if (loss_zero && blockIdx.x == 0 && threadIdx.x == 0) *loss_zero = 0.0f;
  int r = blockIdx.x * 256 + threadIdx.x;
  if (r >= nrows) return;
  if (keys_init) keys_init[r] = 0xFFFFFFFFFFFFFFFFull;
  const float4* p4 = (const float4*)(src + (size_t)r * D);
  uint4* o16 = (uint4*)(b16 + (size_t)r * D);
  float total = 0.0f;
  #pragma unroll
  for (int half = 0; half < 2; ++half) {
    float r8[8];
    #pragma unroll
    for (int i8 = 0; i8 < 16; ++i8) {
      float4 v0 = p4[half * 32 + i8 * 2];
      float4 v1 = p4[half * 32 + i8 * 2 + 1];
      float f[8] = {v0.x, v0.y, v0.z, v0.w, v1.x, v1.y, v1.z, v1.w};
      uint hh[8];
      #pragma unroll
      for (int j = 0; j < 8; ++j) {
        uint u = __float_as_uint(f[j]);
        hh[j] = (u + 0x7FFFu + ((u >> 16) & 1u)) >> 16;   // RNE f32->bf16
      }
      uint4 st;
      st.x = hh[0] | (hh[1] << 16); st.y = hh[2] | (hh[3] << 16);
      st.z = hh[4] | (hh[5] << 16); st.w = hh[6] | (hh[7] << 16);
      o16[half * 16 + i8] = st;
      #pragma unroll
      for (int j = 0; j < 8; ++j) {
        float p = __fmul_rn(f[j], f[j]);
        r8[j] = (i8 == 0) ? p : __fadd_rn(r8[j], p);
      }
    }
    float s = __fadd_rn(__fadd_rn(__fadd_rn(r8[0], r8[1]), __fadd_rn(r8[2], r8[3])),
                        __fadd_rn(__fadd_rn(r8[4], r8[5]), __fadd_rn(r8[6], r8[7])));
    total = (half == 0) ? s : __fadd_rn(total, s);
  }
  sq[r] = total;
}

// Coarse bf16-MFMA filter + exact rescore, K-split across blockIdx.y.
// B staged via global_load_lds (linear LDS dest) with pre-swizzled global
// source: lds[n][s] = global[n][s ^ (n&7)]; reads apply the same XOR.
// Threshold: per-chunk cross-lane refresh for c<8 (burn-in; kills the R5
// flood window), every 4 chunks after (thr is then based on >=512 codes).
// Stale thr is a lower bound -> superset capture -> exact. Overflow (cnt>CAP)
// triggers a full-half rescan in Phase 2 -> correctness never depends on CAP.
__global__ __launch_bounds__(256) void vq_filter_kernel(
    const ushort* __restrict__ xb, const ushort* __restrict__ eb,
    const float* __restrict__ x, const float* __restrict__ emb,
    const float* __restrict__ xsq, const float* __restrict__ esq,
    unsigned long long* __restrict__ keys) {
  __shared__ __align__(16) char ldsb[32768 + BN * CAP * 2 + BN * 4];
  ushort* cand = (ushort*)(ldsb + 32768);
  unsigned* cnt = (unsigned*)(ldsb + 32768 + BN * CAP * 2);

  const int tid = threadIdx.x;
  const int wv = tid >> 6;
  const int l = tid & 63;
  const int lg = l >> 4;     // k-subgroup; C row-subgroup
  const int lc = l & 15;     // A-row / B-col within tile; C col
  const int rowBase = blockIdx.x * BN;
  const int ktBase = blockIdx.y * (KCODES / KSPLIT);

  if (tid < BN) cnt[tid] = 0;

  // A fragments (rows rowBase + wv*16 + lc), k = ks*32 + lg*8 + {0..7}
  const int arow = rowBase + wv * 16 + lc;
  short8 afr[8];
  #pragma unroll
  for (int ks = 0; ks < 8; ++ks)
    afr[ks] = *(const short8*)(xb + (size_t)arow * D + ks * 32 + lg * 8);

  // staging lane roles: lane l covers code n = 2*seg + (l>>5), 16B slot
  // s = l&31; global slot pre-swizzled s ^ (n&7).
  const int st_hi = l >> 5;
  const int st_s = l & 31;

  float mrun[4] = {-1e30f, -1e30f, -1e30f, -1e30f};
  float thr[4] = {-1e30f, -1e30f, -1e30f, -1e30f};

  for (int c = 0; c < CSPLIT; ++c) {
    __syncthreads();   // previous chunk's LDS reads done (also covers cnt init)
    {
      const size_t codeBase = (size_t)ktBase + (size_t)c * CHUNK;
      #pragma unroll
      for (int j = 0; j < 8; ++j) {
        const int seg = wv * 8 + j;
        const int n = 2 * seg + st_hi;
        const int gs = st_s ^ (n & 7);
        gload_lds16(eb + (codeBase + n) * D + gs * 8, ldsb + seg * 1024);
      }
    }
    __syncthreads();   // tile ready (barrier drains vmcnt/lgkm)

    f32x4 acc[4];
    #pragma unroll
    for (int ct = 0; ct < 4; ++ct) acc[ct] = (f32x4){0.f, 0.f, 0.f, 0.f};
    #pragma unroll
    for (int ct = 0; ct < 4; ++ct) {
      const int n = lc + ct * 16;
      const char* rp = ldsb + (size_t)n * 512;
      #pragma unroll
      for (int ks = 0; ks < 8; ++ks) {
        const int sr = ks * 4 + lg;
        short8 bfr = *(const short8*)(rp + ((sr ^ (n & 7)) * 16));
        acc[ct] = __builtin_amdgcn_mfma_f32_16x16x32_bf16(afr[ks], bfr, acc[ct], 0, 0, 0);
      }
    }

    // lane-local running max
    #pragma unroll
    for (int reg = 0; reg < 4; ++reg) {
      float m = fmaxf(fmaxf(acc[0][reg], acc[1][reg]),
                      fmaxf(acc[2][reg], acc[3][reg]));
      mrun[reg] = fmaxf(mrun[reg], m);
    }
    // threshold refresh: every chunk during burn-in, every 4 chunks after
    if (c < 8 || (c & 3) == 0) {
      #pragma unroll
      for (int reg = 0; reg < 4; ++reg) {
        float m = mrun[reg];
        #pragma unroll
        for (int sh = 1; sh < 16; sh <<= 1) m = fmaxf(m, __shfl_xor(m, sh, 64));
        thr[reg] = m - MD;
      }
    }
    // margin appends vs (possibly stale = lower) threshold
    #pragma unroll
    for (int ct = 0; ct < 4; ++ct) {
      #pragma unroll
      for (int reg = 0; reg < 4; ++reg) {
        if (acc[ct][reg] > thr[reg]) {
          int lrow = wv * 16 + lg * 4 + reg;          // C row map (verified)
          unsigned slot = atomicAdd(&cnt[lrow], 1u);
          if (slot < CAP)
            cand[lrow * CAP + slot] =
                (ushort)(ktBase + c * CHUNK + ct * 16 + lc);
        }
      }
    }
  }
  __syncthreads();

  // Phase 2: exact rescore (bit-identical to R1's passing arithmetic);
  // merge K-splits via device-scope atomicMin on u64 keys.
  for (int r16 = 0; r16 < 16; ++r16) {
    const int lrow = wv * 16 + r16;
    const int grow = rowBase + lrow;
    const float xs = xsq[grow];
    const bool ovf = cnt[lrow] > CAP;                 // wave-uniform
    const int total = ovf ? (KCODES / KSPLIT) : (int)cnt[lrow];
    unsigned long long bestk = 0xFFFFFFFFFFFFFFFFull;
    const float4* x4 = (const float4*)(x + (size_t)grow * D);
    for (int ci = l; ci < total; ci += 64) {
      const int idx = ovf ? (ktBase + ci) : (int)cand[lrow * CAP + ci];
      const float4* e4 = (const float4*)(emb + (size_t)idx * D);
      float dot = 0.0f;
      #pragma unroll 8
      for (int q = 0; q < 64; ++q) {
        float4 xv = x4[q], ev = e4[q];
        dot = __builtin_fmaf(xv.x, ev.x, dot);
        dot = __builtin_fmaf(xv.y, ev.y, dot);
        dot = __builtin_fmaf(xv.z, ev.z, dot);
        dot = __builtin_fmaf(xv.w, ev.w, dot);
      }
      float s2 = __fadd_rn(__fsub_rn(xs, __fmul_rn(2.0f, dot)), esq[idx]);
      unsigned long long kk =
          ((unsigned long long)__float_as_uint(s2) << 32) | (unsigned)idx;
      if (kk < bestk) bestk = kk;
    }
    #pragma unroll
    for (int sh = 1; sh < 64; sh <<= 1) {
      unsigned long long o = __shfl_xor(bestk, sh, 64);
      if (o < bestk) bestk = o;
    }
    if (l == 0) atomicMin(&keys[grow], bestk);
  }
}

// Gather quantized rows + write index output + accumulate sum((x-q)^2).
__global__ __launch_bounds__(256) void gather_kernel(
    const float* __restrict__ x, const float* __restrict__ emb,
    const unsigned long long* __restrict__ keys, float* __restrict__ outq,
    float* __restrict__ out_idx, float* __restrict__ loss) {
  const int t = threadIdx.x;
  const int row = blockIdx.x * 64 + (t >> 2);
  const int d0 = (t & 3) * 64;
  const int idx = (int)(unsigned)(keys[row] & 0xFFFFFFFFull);
  if (d0 == 0) out_idx[row] = (float)idx;
  const float4* q4 = (const float4*)(emb + (size_t)idx * D + d0);
  const float4* x4 = (const float4*)(x + (size_t)row * D + d0);
  float4* o4 = (float4*)(outq + (size_t)row * D + d0);
  float s = 0.0f;
  #pragma unroll
  for (int j = 0; j < 16; ++j) {
    float4 q = q4[j];
    float4 xv = x4[j];
    o4[j] = q;
    float e0 = xv.x - q.x; s = __builtin_fmaf(e0, e0, s);
    float e1 = xv.y - q.y; s = __builtin_fmaf(e1, e1, s);
    float e2 = xv.z - q.z; s = __builtin_fmaf(e2, e2, s);
    float e3 = xv.w - q.w; s = __builtin_fmaf(e3, e3, s);
  }
  #pragma unroll
  for (int m = 32; m >= 1; m >>= 1) s += __shfl_xor(s, m, 64);
  __shared__ float wsum[4];
  if ((t & 63) == 0) wsum[t >> 6] = s;
  __syncthreads();
  if (t == 0) atomicAdd(loss, ((wsum[0] + wsum[1]) + (wsum[2] + wsum[3])));
}

__global__ void finalize_kernel(const float* __restrict__ loss,
                                float* __restrict__ out3) {
  if (threadIdx.x == 0 && blockIdx.x == 0) {
    float mean = *loss / 8388608.0f;   // exact: /2^23
    float commit = __fmul_rn(0.25f, mean);
    out3[0] = commit;
    out3[1] = mean;
    out3[2] = __fadd_rn(commit, mean);
  }
}

extern "C" void kernel_launch(void* const* d_in, const int* in_sizes, int n_in,
                              void* d_out, int out_size, void* d_ws, size_t ws_size,
                              hipStream_t stream) {
  const float* x = (const float*)d_in[0];    // [32768, 256] f32
  const float* emb = (const float*)d_in[1];  // [8192, 256] f32
  float* out = (float*)d_out;
  float* ws = (float*)d_ws;

  float* xsq = ws + WS_XSQ;
  float* esq = ws + WS_ESQ;
  float* lossacc = ws + WS_LOSS;
  unsigned long long* keys = (unsigned long long*)(ws + WS_KEYS_F);

  // scratch bf16 copies inside d_out's quantized region (overwritten by gather)
  ushort* xb = (ushort*)out;               // 16.78 MB
  ushort* eb = (ushort*)(out + 4194304);   //  4.19 MB

  prep_kernel<<<NROWS / 256, 256, 0, stream>>>(x, xsq, xb, NROWS, nullptr, keys);
  prep_kernel<<<KCODES / 256, 256, 0, stream>>>(emb, esq, eb, KCODES, lossacc, nullptr);
  dim3 grid(NROWS / BN, KSPLIT);
  vq_filter_kernel<<<grid, 256, 0, stream>>>(xb, eb, x, emb, xsq, esq, keys);
  gather_kernel<<<NROWS / 64, 256, 0, stream>>>(x, emb, keys, out, out + OUT_IDX,
                                                lossacc);
  finalize_kernel<<<1, 64, 0, stream>>>(lossacc, out + OUT_LOSS);
}